// Round 6
// baseline (436.866 us; speedup 1.0000x reference)
//
#include <hip/hip_runtime.h>
#include <hip/hip_bf16.h>
#include <math.h>

// ---------------- types ----------------
typedef __attribute__((ext_vector_type(4))) float   f32x4;
typedef __attribute__((ext_vector_type(8))) short   short8;
typedef __attribute__((ext_vector_type(8))) __bf16  bf16x8;

union SB8 { short8 s; bf16x8 b; };

__device__ __forceinline__ short f2bf(float f) {
  union { float f; unsigned u; } v; v.f = f;
  unsigned r = v.u + 0x7fffu + ((v.u >> 16) & 1u);   // RNE
  return (short)(r >> 16);
}

__device__ __forceinline__ short8 cvt8(f32x4 a, f32x4 b) {
  short8 r;
  r[0] = f2bf(a[0]); r[1] = f2bf(a[1]); r[2] = f2bf(a[2]); r[3] = f2bf(a[3]);
  r[4] = f2bf(b[0]); r[5] = f2bf(b[1]); r[6] = f2bf(b[2]); r[7] = f2bf(b[3]);
  return r;
}

// async global->LDS, 16B per lane; dest is wave-uniform base + lane*16
__device__ __forceinline__ void ldsload16(const short* g, short* l) {
  __builtin_amdgcn_global_load_lds(
      (const __attribute__((address_space(1))) unsigned int*)g,
      (__attribute__((address_space(3))) unsigned int*)l, 16, 0, 0);
}

// Problem constants
#define TT   2048
#define DD   1024        // K of gemm1, N of gemm2
#define HH   704
#define HSS  1408
#define EE   16
#define CAP  2048

// bf16 segment offsets (elements); all 4096-aligned
#define O1  2097152ULL                    // x:  2048*1024
#define O2  13631488ULL                   // w1: 16*704*1024
#define O3  25165824ULL                   // w3
#define O4  36700160ULL                   // w2: 16*1024*704
#define O5  38141952ULL                   // ws1: 1408*1024
#define O6  39583744ULL                   // ws3
#define CVT_TOTAL 41025536ULL             // + ws2
#define CVT_BLOCKS 10016                  // CVT_TOTAL / 4096

// ---------------- fp32 -> bf16 convert (16 elems/thread) ----------------
__global__ __launch_bounds__(256)
void cvt_all(const float* __restrict__ x,  const float* __restrict__ w1,
             const float* __restrict__ w3, const float* __restrict__ w2,
             const float* __restrict__ s1, const float* __restrict__ s3,
             const float* __restrict__ s2, short* __restrict__ dst)
{
  size_t i = ((size_t)blockIdx.x * 256 + threadIdx.x) * 16;
  const float* src;
  if      (i < O1) src = x  + i;
  else if (i < O2) src = w1 + (i - O1);
  else if (i < O3) src = w3 + (i - O2);
  else if (i < O4) src = w2 + (i - O3);
  else if (i < O5) src = s1 + (i - O4);
  else if (i < O6) src = s3 + (i - O5);
  else             src = s2 + (i - O6);
  f32x4 a0 = *(const f32x4*)(src);
  f32x4 a1 = *(const f32x4*)(src + 4);
  f32x4 a2 = *(const f32x4*)(src + 8);
  f32x4 a3 = *(const f32x4*)(src + 12);
  *(short8*)(dst + i)     = cvt8(a0, a1);
  *(short8*)(dst + i + 8) = cvt8(a2, a3);
}

// ---------------- gate: one wave per token, no LDS ----------------
// Lane L: expert e=L&15, d-part p=L>>4. fp64 dots (4-way split chains).
__global__ __launch_bounds__(256)
void gate_kernel(const float* __restrict__ x, const float* __restrict__ gw,
                 const float* __restrict__ gb,
                 int* __restrict__ counts, int* __restrict__ tok,
                 float* __restrict__ wgt, int* __restrict__ eslot)
{
  const int lane = threadIdx.x & 63;
  const int wid  = threadIdx.x >> 6;
  const int t    = blockIdx.x * 4 + wid;
  const int e    = lane & 15;
  const int p    = lane >> 4;

  const float* xp = x + (size_t)t * DD + p * 256;
  const float* gp = gw + (size_t)e * DD + p * 256;

  double a0 = 0.0, a1 = 0.0, a2 = 0.0, a3 = 0.0;
  #pragma unroll 8
  for (int i = 0; i < 64; i++) {
    f32x4 xa = *(const f32x4*)(xp + i * 4);
    f32x4 ga = *(const f32x4*)(gp + i * 4);
    a0 += (double)xa[0] * (double)ga[0];
    a1 += (double)xa[1] * (double)ga[1];
    a2 += (double)xa[2] * (double)ga[2];
    a3 += (double)xa[3] * (double)ga[3];
  }
  double acc = (a0 + a1) + (a2 + a3);
  acc += __shfl_xor(acc, 16);
  acc += __shfl_xor(acc, 32);
  float accf = (float)acc;

  float lf[EE], sc[EE], r[EE];
  #pragma unroll
  for (int j = 0; j < EE; j++) lf[j] = __shfl(accf, j);
  #pragma unroll
  for (int j = 0; j < EE; j++) {
    sc[j] = 1.f / (1.f + expf(-lf[j]));
    r[j] = sc[j] + gb[j];
  }
  float gs[4];
  #pragma unroll
  for (int g = 0; g < 4; g++) {
    float m1 = -1e30f, m2 = -1e30f;
    #pragma unroll
    for (int j = 0; j < 4; j++) {
      float v = r[g * 4 + j];
      if (v > m1) { m2 = m1; m1 = v; }
      else if (v > m2) { m2 = v; }
    }
    gs[g] = m1 + m2;
  }
  int g1 = 0, g2 = -1; float b1 = -1e30f, b2 = -1e30f;
  #pragma unroll
  for (int g = 0; g < 4; g++) {
    if (gs[g] > b1) { b2 = b1; g2 = g1; b1 = gs[g]; g1 = g; }
    else if (gs[g] > b2) { b2 = gs[g]; g2 = g; }
  }
  int idx[4]; float wv[4]; float wsum = 0.f;
  unsigned used = 0;
  #pragma unroll
  for (int k = 0; k < 4; k++) {
    float best = -1e30f; int bi = 0;
    #pragma unroll
    for (int j = 0; j < EE; j++) {
      int g = j >> 2;
      bool keep = (g == g1) || (g == g2);
      if (keep && !((used >> j) & 1) && r[j] > best) { best = r[j]; bi = j; }
    }
    used |= 1u << bi; idx[k] = bi; wv[k] = sc[bi]; wsum += sc[bi];
  }
  float div = wsum < 1e-9f ? 1e-9f : wsum;
  if (lane < 4) {
    float w = wv[lane] / div * 2.5446f;
    int slot = atomicAdd(&counts[idx[lane]], 1);
    tok[idx[lane] * CAP + slot] = t;
    wgt[idx[lane] * CAP + slot] = w;
    eslot[t * 4 + lane] = (idx[lane] << 16) | slot;
  }
}

// ---------------- merged GEMM1 + SwiGLU ----------------
// Tile M=64, N=128 (dual B: W1,W3), BK=64. A in LDS (8KB, XOR-swizzled,
// global_load_lds); B loaded straight to VGPRs (W row-major K-contiguous ->
// each lane's B-frag = one contiguous 16B global load, no cross-wave reuse).
// grid (11, 32, 17): z<16 routed expert z (N=704, Nt<6); z==16 shared (N=1408).
// Wave: 4 m-tiles x 2 n-tiles x 2 matrices = 32 MFMA per BK iter.
__global__ __launch_bounds__(256, 3)
void gemm1_merged(const short* __restrict__ xb, const short* __restrict__ w1b,
                  const short* __restrict__ w3b, const short* __restrict__ ws1b,
                  const short* __restrict__ ws3b, short* __restrict__ act_r,
                  short* __restrict__ act_s, const int* __restrict__ counts,
                  const int* __restrict__ tok)
{
  const int z = blockIdx.z;
  const bool routed = (z < EE);
  const int Mt = blockIdx.y, Nt = blockIdx.x;

  int cnt, N, rowbase = 0;
  const short *W1, *W3;
  short* act;
  if (routed) {
    if (Nt >= 6) return;
    cnt = counts[z];
    if (Mt * 64 >= cnt) return;
    int rb = 0;
    for (int i = 0; i < z; i++) rb += counts[i];
    rowbase = rb;
    N = HH;
    W1 = w1b + (size_t)z * HH * DD;
    W3 = w3b + (size_t)z * HH * DD;
    act = act_r;
  } else {
    cnt = TT; N = HSS; W1 = ws1b; W3 = ws3b; act = act_s;
  }

  __shared__ __align__(16) short lA[64 * 64];   // 8KB

  const int tid = threadIdx.x, lane = tid & 63, wv = tid >> 6;
  const int srow = lane >> 3, scg = (lane & 7) ^ srow;

  // A staging: 8 groups of 8 rows; wave wv stages groups {2wv, 2wv+1}
  const short* pa[2];
  #pragma unroll
  for (int i = 0; i < 2; i++) {
    const int g = wv * 2 + i;
    int arow = Mt * 64 + g * 8 + srow;
    if (routed) {
      int slot = arow < cnt ? arow : cnt - 1;
      arow = tok[z * CAP + slot];
    }
    pa[i] = xb + (size_t)arow * DD + scg * 8;
  }

  // B base pointers (per-lane): row = Nt*128 + (wv*2+ntl)*16 + (lane&15),
  // k-chunk = quad*8
  const int q = lane >> 4, r7 = lane & 7, hi = (lane & 15) >> 3;
  const short* pb1[2]; const short* pb3[2];
  #pragma unroll
  for (int ntl = 0; ntl < 2; ntl++) {
    const int brow = Nt * 128 + (wv * 2 + ntl) * 16 + (lane & 15);
    pb1[ntl] = W1 + (size_t)brow * DD + q * 8;
    pb3[ntl] = W3 + (size_t)brow * DD + q * 8;
  }

  f32x4 acc1[4][2], acc3[4][2];
  #pragma unroll
  for (int i = 0; i < 4; i++) {
    #pragma unroll
    for (int j = 0; j < 2; j++) { acc1[i][j] = (f32x4)0.f; acc3[i][j] = (f32x4)0.f; }
  }

  for (int kk = 0; kk < DD; kk += 64) {
    // issue A DMA + all B register loads (overlap), then barrier
    #pragma unroll
    for (int i = 0; i < 2; i++)
      ldsload16(pa[i] + kk, lA + (wv * 2 + i) * 512);
    SB8 b1f[2][2], b3f[2][2];          // [kc][ntl]
    #pragma unroll
    for (int ntl = 0; ntl < 2; ntl++) {
      b1f[0][ntl].s = *(const short8*)(pb1[ntl] + kk);
      b3f[0][ntl].s = *(const short8*)(pb3[ntl] + kk);
      b1f[1][ntl].s = *(const short8*)(pb1[ntl] + kk + 32);
      b3f[1][ntl].s = *(const short8*)(pb3[ntl] + kk + 32);
    }
    __syncthreads();
    #pragma unroll
    for (int kc = 0; kc < 2; kc++) {
      const int cx = (kc * 4 + q) ^ r7;
      #pragma unroll
      for (int mt = 0; mt < 4; mt++) {
        const int a16 = (2 * mt + hi) * 64 + r7 * 8 + cx;
        SB8 af; af.s = *(const short8*)(lA + a16 * 8);
        acc1[mt][0] = __builtin_amdgcn_mfma_f32_16x16x32_bf16(af.b, b1f[kc][0].b, acc1[mt][0], 0, 0, 0);
        acc1[mt][1] = __builtin_amdgcn_mfma_f32_16x16x32_bf16(af.b, b1f[kc][1].b, acc1[mt][1], 0, 0, 0);
        acc3[mt][0] = __builtin_amdgcn_mfma_f32_16x16x32_bf16(af.b, b3f[kc][0].b, acc3[mt][0], 0, 0, 0);
        acc3[mt][1] = __builtin_amdgcn_mfma_f32_16x16x32_bf16(af.b, b3f[kc][1].b, acc3[mt][1], 0, 0, 0);
      }
    }
    __syncthreads();
  }

  const int quad = lane >> 4, lcol = lane & 15;
  #pragma unroll
  for (int mt = 0; mt < 4; mt++) {
    #pragma unroll
    for (int ntl = 0; ntl < 2; ntl++) {
      const int col = Nt * 128 + (wv * 2 + ntl) * 16 + lcol;
      #pragma unroll
      for (int rg = 0; rg < 4; rg++) {
        const int r = Mt * 64 + mt * 16 + quad * 4 + rg;
        if (r < cnt && col < N) {
          float g = acc1[mt][ntl][rg], u = acc3[mt][ntl][rg];
          float a = g / (1.f + __expf(-g)) * u;
          act[(size_t)(rowbase + r) * N + col] = f2bf(a);
        }
      }
    }
  }
}

// ---------------- merged GEMM2 (down proj) ----------------
// Tile M=64, N=128, BK=64; A in LDS, B in registers. grid (8, 32, 17).
// z<16: routed (K=704, weighted fp32 store to compact outr); z==16: shared
// (K=1408, plain store to y).
__global__ __launch_bounds__(256, 4)
void gemm2_merged(const short* __restrict__ act_r, const short* __restrict__ act_s,
                  const short* __restrict__ w2b, const short* __restrict__ ws2b,
                  float* __restrict__ y, float* __restrict__ outr,
                  const int* __restrict__ counts, const float* __restrict__ wgt)
{
  const int z = blockIdx.z;
  const bool routed = (z < EE);
  const int Mt = blockIdx.y, Nt = blockIdx.x;

  int cnt, Kd, rowbase = 0;
  const short *A, *W;
  if (routed) {
    cnt = counts[z];
    if (Mt * 64 >= cnt) return;
    int rb = 0;
    for (int i = 0; i < z; i++) rb += counts[i];
    rowbase = rb;
    Kd = HH;
    A = act_r + (size_t)rowbase * HH;
    W = w2b + (size_t)z * DD * HH;
  } else {
    cnt = TT; Kd = HSS; A = act_s; W = ws2b;
  }

  __shared__ __align__(16) short lA[64 * 64];

  const int tid = threadIdx.x, lane = tid & 63, wv = tid >> 6;
  const int srow = lane >> 3, scg = (lane & 7) ^ srow;

  const short* pa[2];
  #pragma unroll
  for (int i = 0; i < 2; i++) {
    const int g = wv * 2 + i;
    int arow = Mt * 64 + g * 8 + srow;
    if (arow >= cnt) arow = cnt - 1;
    pa[i] = A + (size_t)arow * Kd + scg * 8;
  }

  const int q = lane >> 4, r7 = lane & 7, hi = (lane & 15) >> 3;
  const short* pb[2];
  #pragma unroll
  for (int ntl = 0; ntl < 2; ntl++) {
    const int brow = Nt * 128 + (wv * 2 + ntl) * 16 + (lane & 15);  // <= 1023
    pb[ntl] = W + (size_t)brow * Kd + q * 8;
  }

  f32x4 acc[4][2];
  #pragma unroll
  for (int i = 0; i < 4; i++) { acc[i][0] = (f32x4)0.f; acc[i][1] = (f32x4)0.f; }

  for (int kk = 0; kk < Kd; kk += 64) {
    #pragma unroll
    for (int i = 0; i < 2; i++)
      ldsload16(pa[i] + kk, lA + (wv * 2 + i) * 512);
    SB8 bf[2][2];
    #pragma unroll
    for (int ntl = 0; ntl < 2; ntl++) {
      bf[0][ntl].s = *(const short8*)(pb[ntl] + kk);
      bf[1][ntl].s = *(const short8*)(pb[ntl] + kk + 32);
    }
    __syncthreads();
    #pragma unroll
    for (int kc = 0; kc < 2; kc++) {
      const int cx = (kc * 4 + q) ^ r7;
      #pragma unroll
      for (int mt = 0; mt < 4; mt++) {
        const int a16 = (2 * mt + hi) * 64 + r7 * 8 + cx;
        SB8 af; af.s = *(const short8*)(lA + a16 * 8);
        acc[mt][0] = __builtin_amdgcn_mfma_f32_16x16x32_bf16(af.b, bf[kc][0].b, acc[mt][0], 0, 0, 0);
        acc[mt][1] = __builtin_amdgcn_mfma_f32_16x16x32_bf16(af.b, bf[kc][1].b, acc[mt][1], 0, 0, 0);
      }
    }
    __syncthreads();
  }

  const int quad = lane >> 4, lcol = lane & 15;
  #pragma unroll
  for (int mt = 0; mt < 4; mt++) {
    #pragma unroll
    for (int ntl = 0; ntl < 2; ntl++) {
      const int col = Nt * 128 + (wv * 2 + ntl) * 16 + lcol;
      #pragma unroll
      for (int rg = 0; rg < 4; rg++) {
        const int slot = Mt * 64 + mt * 16 + quad * 4 + rg;
        const float v = acc[mt][ntl][rg];
        if (routed) {
          if (slot < cnt) {
            const float w = wgt[z * CAP + slot];
            outr[(size_t)(rowbase + slot) * DD + col] = w * v;
          }
        } else {
          y[(size_t)slot * DD + col] = v;
        }
      }
    }
  }
}

// ---------------- combine: y[t] += sum_k outr[offs[e_k]+slot_k] ----------------
__global__ __launch_bounds__(256)
void combine_kernel(float* __restrict__ y, const float* __restrict__ outr,
                    const int* __restrict__ eslot, const int* __restrict__ counts)
{
  const int t = blockIdx.x;
  const int d = threadIdx.x * 4;

  int offs[EE];
  int s = 0;
  #pragma unroll
  for (int i = 0; i < EE; i++) { offs[i] = s; s += counts[i]; }

  f32x4 accv = *(f32x4*)(y + (size_t)t * DD + d);
  #pragma unroll
  for (int k = 0; k < 4; k++) {
    const int es = eslot[t * 4 + k];
    const int row = offs[es >> 16] + (es & 0xFFFF);
    accv += *(const f32x4*)(outr + (size_t)row * DD + d);
  }
  *(f32x4*)(y + (size_t)t * DD + d) = accv;
}

// ---------------- launch ----------------
extern "C" void kernel_launch(void* const* d_in, const int* in_sizes, int n_in,
                              void* d_out, int out_size, void* d_ws, size_t ws_size,
                              hipStream_t stream) {
  const float* x      = (const float*)d_in[0];
  const float* gate_w = (const float*)d_in[1];
  const float* gate_b = (const float*)d_in[2];
  const float* w1     = (const float*)d_in[3];
  const float* w3     = (const float*)d_in[4];
  const float* w2     = (const float*)d_in[5];
  const float* ws1    = (const float*)d_in[6];
  const float* ws3    = (const float*)d_in[7];
  const float* ws2    = (const float*)d_in[8];
  float* y = (float*)d_out;

  char* ws = (char*)d_ws;
  int*   counts = (int*)ws;
  int*   tok    = (int*)(ws + 1024);
  float* wgt    = (float*)(ws + 1024 + (size_t)EE * CAP * 4);
  int*   eslot  = (int*)(ws + 1024 + (size_t)EE * CAP * 8);
  short* bf     = (short*)(ws + 1024 + (size_t)EE * CAP * 8 + (size_t)TT * 16);
  short* xb   = bf;
  short* w1b  = bf + O1;
  short* w3b  = bf + O2;
  short* w2b  = bf + O3;
  short* ws1b = bf + O4;
  short* ws3b = bf + O5;
  short* ws2b = bf + O6;
  short* act_r = bf + CVT_TOTAL;                 // [8192][704] bf16
  short* act_s = act_r + (size_t)8192 * HH;      // [2048][1408] bf16
  // outr (fp32 [8192][1024], 33.5 MB) aliases w1b/w3b (46 MB, dead after gemm1)
  float* outr = (float*)(bf + O1);

  (void)hipMemsetAsync(counts, 0, 256, stream);

  gate_kernel<<<TT / 4, 256, 0, stream>>>(x, gate_w, gate_b, counts, tok, wgt, eslot);

  cvt_all<<<CVT_BLOCKS, 256, 0, stream>>>(x, w1, w3, w2, ws1, ws3, ws2, bf);

  gemm1_merged<<<dim3(11, TT / 64, EE + 1), 256, 0, stream>>>(
      xb, w1b, w3b, ws1b, ws3b, act_r, act_s, counts, tok);

  gemm2_merged<<<dim3(DD / 128, TT / 64, EE + 1), 256, 0, stream>>>(
      act_r, act_s, w2b, ws2b, y, outr, counts, wgt);

  combine_kernel<<<TT, 256, 0, stream>>>(y, outr, eslot, counts);
}